// Round 3
// baseline (9811.777 us; speedup 1.0000x reference)
//
#include <hip/hip_runtime.h>
#include <math.h>

// DreamBeliefTracker — round 3: restructured step.
//  * Wfused = Wi2@WgTop precomputed on device (inp GEMM eliminated; inp is linear).
//  * All weights pre-converted ONCE to transposed f16 hi/lo planes [n][k].
//  * GEMM: 64-thread single-wave blocks, 64x64 tile, full-K, mf=nf=4, XOR-swizzled LDS
//    (conflict-free ds_read_b128), fused epilogue (bias+silu+plane write). 8 blocks/CU.
//  * 5 launches/step: gates(2 jobs) -> gru(+obs conv) -> D(hp,ho concat-A) -> E -> sample(+h1 gather).

typedef _Float16 f16;
typedef _Float16 f16x8 __attribute__((ext_vector_type(8)));
typedef float f32x4 __attribute__((ext_vector_type(4)));

constexpr int kB = 256, kN1 = 1024, kG3N = 3072, kActD = 6, kT = 64;
constexpr float kLoScale = 4096.f;
constexpr float kLoInv = 1.f / 4096.f;

__device__ inline void wr_planes(f16* hi, f16* lo, size_t i, float x) {
  f16 h = (f16)x;
  hi[i] = h;
  lo[i] = (f16)((x - (float)h) * kLoScale);
}

// ------------------------------------------------------------- MFMA GEMM ----
// Single-wave block (64 thr). Tile M=64,N=64, BK=32, full K. A from up to two
// concatenated hi/lo plane sources (row-major [m][k]); W from transposed planes [n][k].
// mode 0: write fp32 raw. mode 1: +bias, silu, write hi/lo planes.
struct MJob {
  const f16 *A1h, *A1l, *A2h, *A2l;   // activation planes
  const f16 *Wph, *Wpl;               // weight planes, transposed [n][K]
  float* outF; f16 *outH, *outL; const float* bias;
  int cols1, K, Nout, mode;
};
struct MJobs { MJob j[2]; };

__global__ __launch_bounds__(64, 2) void k_mgemm(MJobs js) {
  const MJob jb = js.j[blockIdx.z];
  const int m0 = blockIdx.x * 64, n0 = blockIdx.y * 64;
  __shared__ __align__(16) f16 As[2][2048];   // [plane][m*32 + swizzled granule]
  __shared__ __align__(16) f16 Ws[2][2048];   // [plane][n*32 + swizzled granule]
  const int L = threadIdx.x;
  const int rL = L >> 2, gL = L & 3;          // staging: row-in-16, granule
  const int fr = L & 15, quad = L >> 4;       // fragment lane coords

  f32x4 acc1[4][4], acc2[4][4];
#pragma unroll
  for (int i = 0; i < 4; ++i)
#pragma unroll
    for (int j = 0; j < 4; ++j)
#pragma unroll
      for (int r = 0; r < 4; ++r) { acc1[i][j][r] = 0.f; acc2[i][j][r] = 0.f; }

  for (int kg = 0; kg < jb.K; kg += 32) {
    const f16 *Abh, *Abl; int rs, cb;
    if (kg < jb.cols1) { Abh = jb.A1h; Abl = jb.A1l; rs = jb.cols1; cb = kg; }
    else { Abh = jb.A2h; Abl = jb.A2l; rs = jb.K - jb.cols1; cb = kg - jb.cols1; }
    __syncthreads();                      // prior iter's frag reads done
#pragma unroll
    for (int seg = 0; seg < 4; ++seg) {
      const int m = seg * 16 + rL;
      // store granule gL at swizzled slot: slot s holds granule s^((m>>1)&3)
      const int so = m * 32 + ((gL ^ ((m >> 1) & 3)) * 8);
      const size_t ao = (size_t)(m0 + m) * rs + cb + gL * 8;
      *(uint4*)&As[0][so] = *(const uint4*)(Abh + ao);
      *(uint4*)&As[1][so] = *(const uint4*)(Abl + ao);
      const size_t wo = (size_t)(n0 + m) * jb.K + kg + gL * 8;
      *(uint4*)&Ws[0][so] = *(const uint4*)(jb.Wph + wo);
      *(uint4*)&Ws[1][so] = *(const uint4*)(jb.Wpl + wo);
    }
    __syncthreads();
    f16x8 Ah[4], Al[4], Wh[4], Wl[4];
#pragma unroll
    for (int f = 0; f < 4; ++f) {
      const int r = f * 16 + fr;
      const int off = r * 32 + ((quad ^ ((r >> 1) & 3)) * 8);
      Ah[f] = *(const f16x8*)&As[0][off];
      Al[f] = *(const f16x8*)&As[1][off];
      Wh[f] = *(const f16x8*)&Ws[0][off];
      Wl[f] = *(const f16x8*)&Ws[1][off];
    }
#pragma unroll
    for (int mf = 0; mf < 4; ++mf)
#pragma unroll
      for (int nf = 0; nf < 4; ++nf) {
        acc1[mf][nf] = __builtin_amdgcn_mfma_f32_16x16x32_f16(Ah[mf], Wh[nf], acc1[mf][nf], 0, 0, 0);
        acc2[mf][nf] = __builtin_amdgcn_mfma_f32_16x16x32_f16(Ah[mf], Wl[nf], acc2[mf][nf], 0, 0, 0);
        acc2[mf][nf] = __builtin_amdgcn_mfma_f32_16x16x32_f16(Al[mf], Wh[nf], acc2[mf][nf], 0, 0, 0);
      }
  }
#pragma unroll
  for (int mf = 0; mf < 4; ++mf)
#pragma unroll
    for (int nf = 0; nf < 4; ++nf)
#pragma unroll
      for (int r = 0; r < 4; ++r) {
        float s = acc1[mf][nf][r] + acc2[mf][nf][r] * kLoInv;
        const int row = m0 + mf * 16 + quad * 4 + r;
        const int col = n0 + nf * 16 + fr;
        const size_t o = (size_t)row * jb.Nout + col;
        if (jb.mode == 0) {
          jb.outF[o] = s;
        } else {
          s += jb.bias[col];
          s = s * (1.f / (1.f + expf(-s)));
          f16 h = (f16)s;
          jb.outH[o] = h;
          jb.outL[o] = (f16)((s - (float)h) * kLoScale);
        }
      }
}

// ------------------------------------------- one-time weight/plane converters
__global__ __launch_bounds__(256) void k_conv(const float* src, f16* dh, f16* dl) {
  const size_t i = (size_t)blockIdx.x * 256 + threadIdx.x;
  wr_planes(dh, dl, i, src[i]);
}

// src fp32 rows [rowoff, rowoff+K) x srcN cols -> transposed planes [n][K]
__global__ __launch_bounds__(256) void k_convT(const float* src, int rowoff, int srcN,
                                               int K, f16* dh, f16* dl) {
  __shared__ float T[64][65];
  const int k0 = blockIdx.x * 64, n0 = blockIdx.y * 64;
  const int tx = threadIdx.x & 63, ty = threadIdx.x >> 6;
#pragma unroll 4
  for (int i = 0; i < 16; ++i) {
    const int k = ty * 16 + i;
    T[k][tx] = src[(size_t)(rowoff + k0 + k) * srcN + n0 + tx];
  }
  __syncthreads();
#pragma unroll 4
  for (int i = 0; i < 16; ++i) {
    const int n = ty * 16 + i;
    const float x = T[tx][n];
    const size_t o = (size_t)(n0 + n) * K + k0 + tx;
    f16 h = (f16)x;
    dh[o] = h;
    dl[o] = (f16)((x - (float)h) * kLoScale);
  }
}

__global__ __launch_bounds__(256) void k_bfused(const float* Wg, const float* bi2, float* bf) {
  const int n = blockIdx.x * 256 + threadIdx.x;   // 3072
  float s = 0.f;
  for (int j = 0; j < 1024; ++j) s += bi2[j] * Wg[(size_t)j * kG3N + n];
  bf[n] = s;
}

__global__ __launch_bounds__(256) void k_setup(const float* b0, float* bbuf, f16* bh, f16* bl) {
  const size_t i = (size_t)blockIdx.x * 256 + threadIdx.x;
  const float b = b0[i];
  bbuf[i] = b;
  wr_planes(bh, bl, i, b);
}

// ---------------- t=0 finisher: z0-GEMM result + action part + bias + silu --
__global__ __launch_bounds__(256) void k_finish0(const float* P, const float* Wi1,
    const float* bi1, const float* act0, f16* h1h, f16* h1l) {
  const int b = blockIdx.y;
  const int j = blockIdx.x * 256 + threadIdx.x;
  __shared__ float sact[kActD];
  if (threadIdx.x < kActD) sact[threadIdx.x] = act0[b * kActD + threadIdx.x];
  __syncthreads();
  float s = P[(size_t)b * kN1 + j] + bi1[j];
#pragma unroll
  for (int k = 0; k < kActD; ++k) s += sact[k] * Wi1[(size_t)(kN1 + k) * kN1 + j];
  s = s * (1.f / (1.f + expf(-s)));
  wr_planes(h1h, h1l, (size_t)b * kN1 + j, s);
}

// --------- LayerNorm + GRU (sums 2 gate partials) + next-step obs conversion --
__global__ __launch_bounds__(256) void k_gru(const float* Pg0, const float* Pg1,
    const float* bfused, const float* lns, const float* lnb,
    float* bbuf, f16* bh, f16* bl,
    const float* obs_next, f16* oh, f16* ol, int do_obs) {
  const int b = blockIdx.x;
  const int tid = threadIdx.x;
  __shared__ float sh[kG3N];
  __shared__ float red[8];
  float v[12];
  float sum = 0.f, sq = 0.f;
#pragma unroll
  for (int i = 0; i < 12; ++i) {
    const int j = tid + i * 256;
    const size_t o = (size_t)b * kG3N + j;
    const float s = Pg0[o] + Pg1[o] + bfused[j];
    v[i] = s; sum += s; sq += s * s;
  }
  if (do_obs) {
#pragma unroll
    for (int i = 0; i < 4; ++i) {
      const int j = tid + i * 256;
      wr_planes(oh, ol, (size_t)b * kN1 + j, obs_next[(size_t)b * kN1 + j]);
    }
  }
  for (int m = 1; m <= 32; m <<= 1) { sum += __shfl_xor(sum, m); sq += __shfl_xor(sq, m); }
  if ((tid & 63) == 0) { red[(tid >> 6) * 2] = sum; red[(tid >> 6) * 2 + 1] = sq; }
  __syncthreads();
  float ts = 0.f, tq = 0.f;
  for (int w = 0; w < 4; ++w) { ts += red[w * 2]; tq += red[w * 2 + 1]; }
  const float mu   = ts * (1.f / kG3N);
  const float var  = tq * (1.f / kG3N) - mu * mu;
  const float rinv = 1.f / sqrtf(var + 1e-3f);
#pragma unroll
  for (int i = 0; i < 12; ++i) {
    const int j = tid + i * 256;
    sh[j] = (v[i] - mu) * rinv * lns[j] + lnb[j];
  }
  __syncthreads();
#pragma unroll
  for (int i = 0; i < 4; ++i) {
    const int j = tid + i * 256;
    const float r = sh[j], c = sh[kN1 + j], u = sh[2 * kN1 + j];
    const float reset = 1.f / (1.f + expf(-r));
    const float cand  = tanhf(reset * c);
    const float upd   = 1.f / (1.f + expf(-(u - 1.f)));   // UPDATE_BIAS = -1
    const size_t o = (size_t)b * kN1 + j;
    const float bn = upd * cand + (1.f - upd) * bbuf[o];
    bbuf[o] = bn;
    wr_planes(bh, bl, o, bn);
  }
}

// -------- softmax/unimix/KL + Gumbel argmax + fused h1 gather for next step --
__global__ __launch_bounds__(1024) void k_sample(const float* Ppl, const float* Pol,
    const float* bp2, const float* bo2, const float* unz_t, float* loss_t,
    const float* Wi1, const float* bi1, const float* act_next,
    f16* h1h, f16* h1l, int do_gather) {
  const int b = blockIdx.x;
  const int tid = threadIdx.x;
  const size_t o = (size_t)b * kN1 + tid;
  float lp = Ppl[o] + bp2[tid];
  float lo = Pol[o] + bo2[tid];
  lp = fminf(fmaxf(lp, -20.f), 20.f);
  lo = fminf(fmaxf(lo, -20.f), 20.f);
  float mp = lp, mo = lo;
  for (int m = 1; m <= 16; m <<= 1) { mp = fmaxf(mp, __shfl_xor(mp, m)); mo = fmaxf(mo, __shfl_xor(mo, m)); }
  const float ep = expf(lp - mp), eo = expf(lo - mo);
  float sp = ep, so = eo;
  for (int m = 1; m <= 16; m <<= 1) { sp += __shfl_xor(sp, m); so += __shfl_xor(so, m); }
  const float pp = (ep / sp) * 0.99f + (0.01f / 32.f);
  const float po = (eo / so) * 0.99f + (0.01f / 32.f);
  float kt = po * (logf(po + 1e-8f) - logf(pp + 1e-8f));
  for (int m = 1; m <= 16; m <<= 1) kt += __shfl_xor(kt, m);
  const float u = unz_t[o];
  const float g = -logf(-logf(u + 1e-6f) + 1e-6f);
  float vv = logf(fmaxf(po, 1e-6f)) + g;
  int ii = tid & 31;
  for (int m = 1; m <= 16; m <<= 1) {
    const float vo = __shfl_xor(vv, m);
    const int   io = __shfl_xor(ii, m);
    if (vo > vv || (vo == vv && io < ii)) { vv = vo; ii = io; }   // first-max ties
  }
  __shared__ float skl[32];
  __shared__ int   sidx[32];
  if ((tid & 31) == 0) { skl[tid >> 5] = kt; sidx[tid >> 5] = ii; }
  __syncthreads();
  if (tid == 0) {
    float kl = 0.f;
    for (int gg = 0; gg < 32; ++gg) kl += skl[gg];
    const float dl = fmaxf(kl, 0.1f);
    loss_t[b] = 1.0f * dl + 0.1f * dl;
  }
  if (do_gather) {   // h1 for next step: one-hot gather + action part + silu
    float s = bi1[tid];
#pragma unroll
    for (int gg = 0; gg < 32; ++gg)
      s += Wi1[(size_t)(gg * 32 + sidx[gg]) * kN1 + tid];
#pragma unroll
    for (int k = 0; k < kActD; ++k)
      s += act_next[b * kActD + k] * Wi1[(size_t)(kN1 + k) * kN1 + tid];
    s = s * (1.f / (1.f + expf(-s)));
    wr_planes(h1h, h1l, o, s);
  }
}

// ---------------------------------------------------------------------------
extern "C" void kernel_launch(void* const* d_in, const int* in_sizes, int n_in,
                              void* d_out, int out_size, void* d_ws, size_t ws_size,
                              hipStream_t stream) {
  const float* b0   = (const float*)d_in[0];
  const float* z0   = (const float*)d_in[1];
  const float* acts = (const float*)d_in[2];
  const float* obs  = (const float*)d_in[3];
  const float* unz  = (const float*)d_in[4];
  const float* Wi1  = (const float*)d_in[5];
  const float* bi1  = (const float*)d_in[6];
  const float* Wi2  = (const float*)d_in[7];
  const float* bi2  = (const float*)d_in[8];
  const float* Wg   = (const float*)d_in[9];
  const float* lns  = (const float*)d_in[10];
  const float* lnb  = (const float*)d_in[11];
  const float* Wo1  = (const float*)d_in[12];
  const float* bo1  = (const float*)d_in[13];
  const float* Wo2  = (const float*)d_in[14];
  const float* bo2  = (const float*)d_in[15];
  const float* Wp1  = (const float*)d_in[16];
  const float* bp1  = (const float*)d_in[17];
  const float* Wp2  = (const float*)d_in[18];
  const float* bp2  = (const float*)d_in[19];
  float* out = (float*)d_out;

  // ---- workspace carve (~84 MB). Region0 (first ~13.6 MB) doubles as the
  //      one-time Wfused fp32 staging buffer (dead before its members are live).
  char* wsb = (char*)d_ws;
  size_t off = 0;
  auto allocB = [&](size_t bytes) { char* p = wsb + off; off += (bytes + 255) & ~(size_t)255; return p; };
  const size_t PL = (size_t)kB * kN1;
  float* Wfused_tmp = (float*)wsb;                  // overlays region0 (prologue only)
  // --- region0 members (13.6 MB total >= 12.6 MB needed by Wfused_tmp) ---
  float* Pg0 = (float*)allocB((size_t)kB * kG3N * 4);
  float* Pg1 = (float*)allocB((size_t)kB * kG3N * 4);
  float* Ppl = (float*)allocB(PL * 4);
  float* Pol = (float*)allocB(PL * 4);
  f16* hph = (f16*)allocB(PL * 2);  f16* hpl = (f16*)allocB(PL * 2);
  f16* hoh = (f16*)allocB(PL * 2);  f16* hol = (f16*)allocB(PL * 2);
  f16* h1h = (f16*)allocB(PL * 2);  f16* h1l = (f16*)allocB(PL * 2);
  f16* bh  = (f16*)allocB(PL * 2);  f16* bl  = (f16*)allocB(PL * 2);
  f16* o1h = (f16*)allocB(PL * 2);  f16* o1l = (f16*)allocB(PL * 2);   // obs planes, odd t
  // --- outside region0 ---
  f16* o0h = (f16*)allocB(PL * 2);  f16* o0l = (f16*)allocB(PL * 2);   // obs planes, even t
  f16* z0h = (f16*)allocB(PL * 2);  f16* z0l = (f16*)allocB(PL * 2);
  float* bbuf   = (float*)allocB(PL * 4);
  float* bfused = (float*)allocB((size_t)kG3N * 4);
  const size_t W1 = (size_t)kN1 * kN1;              // 1M elements
  f16* WfTh = (f16*)allocB(W1 * 3 * 2);  f16* WfTl = (f16*)allocB(W1 * 3 * 2);   // [3072][1024]
  f16* WgBh = (f16*)allocB(W1 * 3 * 2);  f16* WgBl = (f16*)allocB(W1 * 3 * 2);   // [3072][1024]
  f16* WgTh = (f16*)allocB(W1 * 3 * 2);  f16* WgTl = (f16*)allocB(W1 * 3 * 2);   // [3072][1024]
  f16* Wi2h = (f16*)allocB(W1 * 2);      f16* Wi2l = (f16*)allocB(W1 * 2);       // row-major [1024][1024]
  f16* Wi1Th = (f16*)allocB(W1 * 2);     f16* Wi1Tl = (f16*)allocB(W1 * 2);      // [1024][1024]
  f16* Wo1Th = (f16*)allocB(W1 * 2 * 2); f16* Wo1Tl = (f16*)allocB(W1 * 2 * 2);  // [1024][2048]
  f16* Wp1Th = (f16*)allocB(W1 * 2);     f16* Wp1Tl = (f16*)allocB(W1 * 2);
  f16* Wp2Th = (f16*)allocB(W1 * 2);     f16* Wp2Tl = (f16*)allocB(W1 * 2);
  f16* Wo2Th = (f16*)allocB(W1 * 2);     f16* Wo2Tl = (f16*)allocB(W1 * 2);

  // ================= prologue (one-time per call) =================
  k_convT<<<dim3(16, 48), 256, 0, stream>>>(Wg, 0, kG3N, 1024, WgTh, WgTl);
  k_convT<<<dim3(16, 48), 256, 0, stream>>>(Wg, 1024, kG3N, 1024, WgBh, WgBl);
  k_convT<<<dim3(16, 16), 256, 0, stream>>>(Wi1, 0, kN1, 1024, Wi1Th, Wi1Tl);
  k_convT<<<dim3(32, 16), 256, 0, stream>>>(Wo1, 0, kN1, 2048, Wo1Th, Wo1Tl);
  k_convT<<<dim3(16, 16), 256, 0, stream>>>(Wp1, 0, kN1, 1024, Wp1Th, Wp1Tl);
  k_convT<<<dim3(16, 16), 256, 0, stream>>>(Wp2, 0, kN1, 1024, Wp2Th, Wp2Tl);
  k_convT<<<dim3(16, 16), 256, 0, stream>>>(Wo2, 0, kN1, 1024, Wo2Th, Wo2Tl);
  k_conv<<<dim3(4096), 256, 0, stream>>>(Wi2, Wi2h, Wi2l);
  k_bfused<<<dim3(12), 256, 0, stream>>>(Wg, bi2, bfused);
  {  // Wfused = Wi2 @ WgTop  (fp32 out into overlay), then -> transposed planes
    MJobs J{};
    J.j[0] = { Wi2h, Wi2l, nullptr, nullptr, WgTh, WgTl, Wfused_tmp, nullptr, nullptr, nullptr,
               1024, 1024, kG3N, 0 };
    J.j[1] = J.j[0];
    k_mgemm<<<dim3(16, 48, 1), 64, 0, stream>>>(J);
  }
  k_convT<<<dim3(16, 48), 256, 0, stream>>>(Wfused_tmp, 0, kG3N, 1024, WfTh, WfTl);
  // state / t=0 inputs (after overlay is dead)
  k_setup<<<dim3(1024), 256, 0, stream>>>(b0, bbuf, bh, bl);
  k_conv<<<dim3(1024), 256, 0, stream>>>(z0, z0h, z0l);
  k_conv<<<dim3(1024), 256, 0, stream>>>(obs, o0h, o0l);            // obs[0]
  {  // h1(t=0) = silu(z0 @ Wi1Top + act + bi1)
    MJobs J{};
    J.j[0] = { z0h, z0l, nullptr, nullptr, Wi1Th, Wi1Tl, Ppl, nullptr, nullptr, nullptr,
               1024, 1024, kN1, 0 };
    J.j[1] = J.j[0];
    k_mgemm<<<dim3(4, 16, 1), 64, 0, stream>>>(J);
  }
  k_finish0<<<dim3(4, kB), 256, 0, stream>>>(Ppl, Wi1, bi1, acts, h1h, h1l);

  // ================= the scan =================
  for (int t = 0; t < kT; ++t) {
    const float* unz_t = unz + (size_t)t * kB * kN1;
    f16* oth = (t & 1) ? o1h : o0h;
    f16* otl = (t & 1) ? o1l : o0l;
    f16* onh = (t & 1) ? o0h : o1h;
    f16* onl = (t & 1) ? o0l : o1l;

    {  // gates partials: Pg0 = h1 @ Wfused ; Pg1 = b @ WgBot
      MJobs J{};
      J.j[0] = { h1h, h1l, nullptr, nullptr, WfTh, WfTl, Pg0, nullptr, nullptr, nullptr,
                 1024, 1024, kG3N, 0 };
      J.j[1] = { bh, bl, nullptr, nullptr, WgBh, WgBl, Pg1, nullptr, nullptr, nullptr,
                 1024, 1024, kG3N, 0 };
      k_mgemm<<<dim3(4, 48, 2), 64, 0, stream>>>(J);
    }
    k_gru<<<dim3(kB), 256, 0, stream>>>(Pg0, Pg1, bfused, lns, lnb, bbuf, bh, bl,
                                        obs + (size_t)(t + 1) * kB * kN1, onh, onl,
                                        (t < kT - 1) ? 1 : 0);
    {  // D: hp = silu(b@Wp1+bp1) ; ho = silu([obs,b]@Wo1+bo1)
      MJobs J{};
      J.j[0] = { bh, bl, nullptr, nullptr, Wp1Th, Wp1Tl, nullptr, hph, hpl, bp1,
                 1024, 1024, kN1, 1 };
      J.j[1] = { oth, otl, bh, bl, Wo1Th, Wo1Tl, nullptr, hoh, hol, bo1,
                 1024, 2048, kN1, 1 };
      k_mgemm<<<dim3(4, 16, 2), 64, 0, stream>>>(J);
    }
    {  // E: prior / post logits (raw fp32; biases added in sample)
      MJobs J{};
      J.j[0] = { hph, hpl, nullptr, nullptr, Wp2Th, Wp2Tl, Ppl, nullptr, nullptr, nullptr,
                 1024, 1024, kN1, 0 };
      J.j[1] = { hoh, hol, nullptr, nullptr, Wo2Th, Wo2Tl, Pol, nullptr, nullptr, nullptr,
                 1024, 1024, kN1, 0 };
      k_mgemm<<<dim3(4, 16, 2), 64, 0, stream>>>(J);
    }
    k_sample<<<dim3(kB), 1024, 0, stream>>>(Ppl, Pol, bp2, bo2, unz_t,
                                            out + (size_t)t * kB,
                                            Wi1, bi1, acts + (size_t)(t + 1) * kB * kActD,
                                            h1h, h1l, (t < kT - 1) ? 1 : 0);
  }
}

// Round 4
// 5974.814 us; speedup vs baseline: 1.6422x; 1.6422x over previous
//
#include <hip/hip_runtime.h>
#include <math.h>

// DreamBeliefTracker — round 4: latency-hiding MFMA engine.
//  * Keeps round-3 algebra: Wfused=Wi2@WgTop (inp GEMM gone), f16 hi/lo planes (error ~2^-22,
//    rounds 1-3 all absmax 0.0), one-hot z gather, fused consumers.
//  * New GEMM: 256-thr blocks, tile 128x64, BK=32, DOUBLE-BUFFERED global_load_lds prefetch
//    (DMA for tile k+1 issued before computing tile k), split-K for block count.
//  * Per step: k_mgemm(gates,384blk) -> k_gru -> k_mgemm(D,192blk) -> k_comb -> k_mgemm(E,128blk)
//    -> k_sample. 6 launches/step.

typedef _Float16 f16;
typedef _Float16 f16x8 __attribute__((ext_vector_type(8)));
typedef float f32x4 __attribute__((ext_vector_type(4)));

constexpr int kB = 256, kN1 = 1024, kG3N = 3072, kActD = 6, kT = 64;
constexpr float kLoScale = 4096.f;
constexpr float kLoInv = 1.f / 4096.f;

__device__ __forceinline__ void wr_planes(f16* hi, f16* lo, size_t i, float x) {
  f16 h = (f16)x;
  hi[i] = h;
  lo[i] = (f16)((x - (float)h) * kLoScale);
}

__device__ __forceinline__ void glds16(const f16* g, f16* l) {
  __builtin_amdgcn_global_load_lds(
      (const __attribute__((address_space(1))) unsigned int*)g,
      (__attribute__((address_space(3))) unsigned int*)l, 16, 0, 0);
}

// ------------------------------------------------------------- MFMA GEMM ----
// 256 threads (4 waves, 2m x 2n), tile 128x64, BK=32. A from up to two concatenated
// hi/lo plane sources (row-major [m][k]); W transposed planes [n][K]. fp32 out.
struct MJob {
  const f16 *A1h, *A1l, *A2h, *A2l;
  const f16 *Wph, *Wpl;
  float* outF;
  int cols1, K, Nout, k0, klen, ny;
};
struct MJobs { MJob j[6]; };

__global__ __launch_bounds__(256, 2) void k_mgemm(MJobs js) {
  const MJob jb = js.j[blockIdx.z];
  if ((int)blockIdx.y >= jb.ny) return;
  const int m0 = blockIdx.x * 128, n0 = blockIdx.y * 64;
  // frag-packed LDS: [buf][plane][panel][lane][8 f16] — DMA dest = base + lane*16
  __shared__ __align__(16) f16 As[2][2][8][64][8];   // 32 KB
  __shared__ __align__(16) f16 Ws[2][2][4][64][8];   // 16 KB
  const int t = threadIdx.x, wave = t >> 6, lane = t & 63;
  const int rlo = lane & 15, khi = (lane >> 4) * 8;
  const int wmf = (wave & 1) * 4, wnf = (wave >> 1) * 2;

  f32x4 acc1[4][2], acc2[4][2];
#pragma unroll
  for (int i = 0; i < 4; ++i)
#pragma unroll
    for (int j = 0; j < 2; ++j)
#pragma unroll
      for (int r = 0; r < 4; ++r) { acc1[i][j][r] = 0.f; acc2[i][j][r] = 0.f; }

  auto issueTile = [&](int it, int buf) {
    const int kg = jb.k0 + it * 32;
    const f16 *h, *l; int rs, cb;
    if (kg < jb.cols1) { h = jb.A1h; l = jb.A1l; rs = jb.cols1; cb = kg; }
    else { h = jb.A2h; l = jb.A2l; rs = jb.K - jb.cols1; cb = kg - jb.cols1; }
#pragma unroll
    for (int i = 0; i < 2; ++i) {                     // each wave: 2 A-panels x 2 planes
      const int mf = wave * 2 + i;
      const size_t go = (size_t)(m0 + mf * 16 + rlo) * rs + cb + khi;
      glds16(h + go, &As[buf][0][mf][0][0]);
      glds16(l + go, &As[buf][1][mf][0][0]);
    }
    const size_t wo = (size_t)(n0 + wave * 16 + rlo) * jb.K + kg + khi;  // 1 W-panel x 2 planes
    glds16(jb.Wph + wo, &Ws[buf][0][wave][0][0]);
    glds16(jb.Wpl + wo, &Ws[buf][1][wave][0][0]);
  };

  issueTile(0, 0);
  __syncthreads();
  const int niter = jb.klen >> 5;
  for (int it = 0; it < niter; ++it) {
    const int buf = it & 1;
    if (it + 1 < niter) issueTile(it + 1, buf ^ 1);   // DMA in flight during compute
    f16x8 Af[4][2], Wf[2][2];
#pragma unroll
    for (int mf = 0; mf < 4; ++mf) {
      Af[mf][0] = *(const f16x8*)&As[buf][0][wmf + mf][lane][0];
      Af[mf][1] = *(const f16x8*)&As[buf][1][wmf + mf][lane][0];
    }
#pragma unroll
    for (int nf = 0; nf < 2; ++nf) {
      Wf[nf][0] = *(const f16x8*)&Ws[buf][0][wnf + nf][lane][0];
      Wf[nf][1] = *(const f16x8*)&Ws[buf][1][wnf + nf][lane][0];
    }
#pragma unroll
    for (int mf = 0; mf < 4; ++mf)
#pragma unroll
      for (int nf = 0; nf < 2; ++nf) {
        acc1[mf][nf] = __builtin_amdgcn_mfma_f32_16x16x32_f16(Af[mf][0], Wf[nf][0], acc1[mf][nf], 0, 0, 0);
        acc2[mf][nf] = __builtin_amdgcn_mfma_f32_16x16x32_f16(Af[mf][0], Wf[nf][1], acc2[mf][nf], 0, 0, 0);
        acc2[mf][nf] = __builtin_amdgcn_mfma_f32_16x16x32_f16(Af[mf][1], Wf[nf][0], acc2[mf][nf], 0, 0, 0);
      }
    __syncthreads();                                  // drains DMA for next buffer
  }
  const int orow = m0 + (wave & 1) * 64, ocol = n0 + (wave >> 1) * 32;
#pragma unroll
  for (int mf = 0; mf < 4; ++mf)
#pragma unroll
    for (int nf = 0; nf < 2; ++nf)
#pragma unroll
      for (int r = 0; r < 4; ++r) {
        const int row = orow + mf * 16 + (lane >> 4) * 4 + r;
        const int col = ocol + nf * 16 + rlo;
        jb.outF[(size_t)row * jb.Nout + col] = acc1[mf][nf][r] + acc2[mf][nf][r] * kLoInv;
      }
}

// ----------------------------------- D combine: sum partials + bias + silu --
struct CJob { const float* P; int nparts; const float* bias; f16* oh; f16* ol; };
struct CJobs { CJob j[2]; };

__global__ __launch_bounds__(256) void k_comb(CJobs js) {
  const CJob jb = js.j[blockIdx.y];
  const int i = blockIdx.x * 256 + threadIdx.x;
  float s = 0.f;
  for (int p = 0; p < jb.nparts; ++p) s += jb.P[(size_t)p * (kB * kN1) + i];
  s += jb.bias[i & (kN1 - 1)];
  s = s * (1.f / (1.f + expf(-s)));
  wr_planes(jb.oh, jb.ol, i, s);
}

// ------------------------------------------- one-time weight/plane converters
__global__ __launch_bounds__(256) void k_conv(const float* src, f16* dh, f16* dl) {
  const size_t i = (size_t)blockIdx.x * 256 + threadIdx.x;
  wr_planes(dh, dl, i, src[i]);
}

// src fp32 rows [rowoff, rowoff+K) x srcN cols -> transposed planes [n][K]
__global__ __launch_bounds__(256) void k_convT(const float* src, int rowoff, int srcN,
                                               int K, f16* dh, f16* dl) {
  __shared__ float T[64][65];
  const int k0 = blockIdx.x * 64, n0 = blockIdx.y * 64;
  const int tx = threadIdx.x & 63, ty = threadIdx.x >> 6;
#pragma unroll 4
  for (int i = 0; i < 16; ++i) {
    const int k = ty * 16 + i;
    T[k][tx] = src[(size_t)(rowoff + k0 + k) * srcN + n0 + tx];
  }
  __syncthreads();
#pragma unroll 4
  for (int i = 0; i < 16; ++i) {
    const int n = ty * 16 + i;
    const float x = T[tx][n];
    const size_t o = (size_t)(n0 + n) * K + k0 + tx;
    f16 h = (f16)x;
    dh[o] = h;
    dl[o] = (f16)((x - (float)h) * kLoScale);
  }
}

__global__ __launch_bounds__(256) void k_bfused(const float* Wg, const float* bi2, float* bf) {
  const int n = blockIdx.x * 256 + threadIdx.x;
  float s = 0.f;
  for (int j = 0; j < 1024; ++j) s += bi2[j] * Wg[(size_t)j * kG3N + n];
  bf[n] = s;
}

__global__ __launch_bounds__(256) void k_setup(const float* b0, float* bbuf, f16* bh, f16* bl) {
  const size_t i = (size_t)blockIdx.x * 256 + threadIdx.x;
  const float b = b0[i];
  bbuf[i] = b;
  wr_planes(bh, bl, i, b);
}

// ---------------- t=0 finisher: z0-GEMM result + action part + bias + silu --
__global__ __launch_bounds__(256) void k_finish0(const float* P, const float* Wi1,
    const float* bi1, const float* act0, f16* h1h, f16* h1l) {
  const int b = blockIdx.y;
  const int j = blockIdx.x * 256 + threadIdx.x;
  __shared__ float sact[kActD];
  if (threadIdx.x < kActD) sact[threadIdx.x] = act0[b * kActD + threadIdx.x];
  __syncthreads();
  float s = P[(size_t)b * kN1 + j] + bi1[j];
#pragma unroll
  for (int k = 0; k < kActD; ++k) s += sact[k] * Wi1[(size_t)(kN1 + k) * kN1 + j];
  s = s * (1.f / (1.f + expf(-s)));
  wr_planes(h1h, h1l, (size_t)b * kN1 + j, s);
}

// --------- LayerNorm + GRU (sums 4 gate partials) + next-step obs conversion --
__global__ __launch_bounds__(256) void k_gru(const float* Pg, const float* bfused,
    const float* lns, const float* lnb, float* bbuf, f16* bh, f16* bl,
    const float* obs_next, f16* oh, f16* ol, int do_obs) {
  const int b = blockIdx.x;
  const int tid = threadIdx.x;
  const size_t S3 = (size_t)kB * kG3N;
  __shared__ float sh[kG3N];
  __shared__ float red[8];
  float v[12];
  float sum = 0.f, sq = 0.f;
#pragma unroll
  for (int i = 0; i < 12; ++i) {
    const int j = tid + i * 256;
    const size_t o = (size_t)b * kG3N + j;
    const float s = Pg[o] + Pg[S3 + o] + Pg[2 * S3 + o] + Pg[3 * S3 + o] + bfused[j];
    v[i] = s; sum += s; sq += s * s;
  }
  if (do_obs) {
#pragma unroll
    for (int i = 0; i < 4; ++i) {
      const int j = tid + i * 256;
      wr_planes(oh, ol, (size_t)b * kN1 + j, obs_next[(size_t)b * kN1 + j]);
    }
  }
  for (int m = 1; m <= 32; m <<= 1) { sum += __shfl_xor(sum, m); sq += __shfl_xor(sq, m); }
  if ((tid & 63) == 0) { red[(tid >> 6) * 2] = sum; red[(tid >> 6) * 2 + 1] = sq; }
  __syncthreads();
  float ts = 0.f, tq = 0.f;
  for (int w = 0; w < 4; ++w) { ts += red[w * 2]; tq += red[w * 2 + 1]; }
  const float mu   = ts * (1.f / kG3N);
  const float var  = tq * (1.f / kG3N) - mu * mu;
  const float rinv = 1.f / sqrtf(var + 1e-3f);
#pragma unroll
  for (int i = 0; i < 12; ++i) {
    const int j = tid + i * 256;
    sh[j] = (v[i] - mu) * rinv * lns[j] + lnb[j];
  }
  __syncthreads();
#pragma unroll
  for (int i = 0; i < 4; ++i) {
    const int j = tid + i * 256;
    const float r = sh[j], c = sh[kN1 + j], u = sh[2 * kN1 + j];
    const float reset = 1.f / (1.f + expf(-r));
    const float cand  = tanhf(reset * c);
    const float upd   = 1.f / (1.f + expf(-(u - 1.f)));   // UPDATE_BIAS = -1
    const size_t o = (size_t)b * kN1 + j;
    const float bn = upd * cand + (1.f - upd) * bbuf[o];
    bbuf[o] = bn;
    wr_planes(bh, bl, o, bn);
  }
}

// -- softmax/unimix/KL + Gumbel argmax + fused h1 gather (sums 2+2 E partials) --
__global__ __launch_bounds__(1024) void k_sample(const float* PE,
    const float* bp2, const float* bo2, const float* unz_t, float* loss_t,
    const float* Wi1, const float* bi1, const float* act_next,
    f16* h1h, f16* h1l, int do_gather) {
  const int b = blockIdx.x;
  const int tid = threadIdx.x;
  const size_t PL = (size_t)kB * kN1;
  const size_t o = (size_t)b * kN1 + tid;
  float lp = PE[o] + PE[PL + o] + bp2[tid];
  float lo = PE[2 * PL + o] + PE[3 * PL + o] + bo2[tid];
  lp = fminf(fmaxf(lp, -20.f), 20.f);
  lo = fminf(fmaxf(lo, -20.f), 20.f);
  float mp = lp, mo = lo;
  for (int m = 1; m <= 16; m <<= 1) { mp = fmaxf(mp, __shfl_xor(mp, m)); mo = fmaxf(mo, __shfl_xor(mo, m)); }
  const float ep = expf(lp - mp), eo = expf(lo - mo);
  float sp = ep, so = eo;
  for (int m = 1; m <= 16; m <<= 1) { sp += __shfl_xor(sp, m); so += __shfl_xor(so, m); }
  const float pp = (ep / sp) * 0.99f + (0.01f / 32.f);
  const float po = (eo / so) * 0.99f + (0.01f / 32.f);
  float kt = po * (logf(po + 1e-8f) - logf(pp + 1e-8f));
  for (int m = 1; m <= 16; m <<= 1) kt += __shfl_xor(kt, m);
  const float u = unz_t[o];
  const float g = -logf(-logf(u + 1e-6f) + 1e-6f);
  float vv = logf(fmaxf(po, 1e-6f)) + g;
  int ii = tid & 31;
  for (int m = 1; m <= 16; m <<= 1) {
    const float vo = __shfl_xor(vv, m);
    const int   io = __shfl_xor(ii, m);
    if (vo > vv || (vo == vv && io < ii)) { vv = vo; ii = io; }   // first-max ties
  }
  __shared__ float skl[32];
  __shared__ int   sidx[32];
  if ((tid & 31) == 0) { skl[tid >> 5] = kt; sidx[tid >> 5] = ii; }
  __syncthreads();
  if (tid == 0) {
    float kl = 0.f;
    for (int gg = 0; gg < 32; ++gg) kl += skl[gg];
    const float dl = fmaxf(kl, 0.1f);
    loss_t[b] = 1.0f * dl + 0.1f * dl;
  }
  if (do_gather) {
    float s = bi1[tid];
#pragma unroll
    for (int gg = 0; gg < 32; ++gg)
      s += Wi1[(size_t)(gg * 32 + sidx[gg]) * kN1 + tid];
#pragma unroll
    for (int k = 0; k < kActD; ++k)
      s += act_next[b * kActD + k] * Wi1[(size_t)(kN1 + k) * kN1 + tid];
    s = s * (1.f / (1.f + expf(-s)));
    wr_planes(h1h, h1l, o, s);
  }
}

// ---------------------------------------------------------------------------
extern "C" void kernel_launch(void* const* d_in, const int* in_sizes, int n_in,
                              void* d_out, int out_size, void* d_ws, size_t ws_size,
                              hipStream_t stream) {
  const float* b0   = (const float*)d_in[0];
  const float* z0   = (const float*)d_in[1];
  const float* acts = (const float*)d_in[2];
  const float* obs  = (const float*)d_in[3];
  const float* unz  = (const float*)d_in[4];
  const float* Wi1  = (const float*)d_in[5];
  const float* bi1  = (const float*)d_in[6];
  const float* Wi2  = (const float*)d_in[7];
  const float* bi2  = (const float*)d_in[8];
  const float* Wg   = (const float*)d_in[9];
  const float* lns  = (const float*)d_in[10];
  const float* lnb  = (const float*)d_in[11];
  const float* Wo1  = (const float*)d_in[12];
  const float* bo1  = (const float*)d_in[13];
  const float* Wo2  = (const float*)d_in[14];
  const float* bo2  = (const float*)d_in[15];
  const float* Wp1  = (const float*)d_in[16];
  const float* bp1  = (const float*)d_in[17];
  const float* Wp2  = (const float*)d_in[18];
  const float* bp2  = (const float*)d_in[19];
  float* out = (float*)d_out;

  char* wsb = (char*)d_ws;
  size_t off = 0;
  auto allocB = [&](size_t bytes) { char* p = wsb + off; off += (bytes + 255) & ~(size_t)255; return p; };
  const size_t PL = (size_t)kB * kN1;
  const size_t S3 = (size_t)kB * kG3N;
  const size_t W1 = (size_t)kN1 * kN1;

  // region A: gate partials (4 x 256x3072 fp32 = 12 MB) — overlays Wfused_tmp (1024x3072 fp32)
  float* Pg = (float*)allocB(4 * S3 * 4);
  float* Wfused_tmp = Pg;
  // region B: WgT planes (prologue-only, 12.6 MB) — overlays PD (6 MB) + PE (4 MB)
  f16* WgTh = (f16*)allocB(W1 * 3 * 2);
  f16* WgTl = (f16*)allocB(W1 * 3 * 2);
  float* PD = (float*)WgTh;                   // 6 x 256x1024 fp32
  float* PE = (float*)WgTl;                   // 4 x 256x1024 fp32
  // persistent planes / state
  f16* h1h = (f16*)allocB(PL * 2);  f16* h1l = (f16*)allocB(PL * 2);
  f16* bh  = (f16*)allocB(PL * 2);  f16* bl  = (f16*)allocB(PL * 2);
  f16* hph = (f16*)allocB(PL * 2);  f16* hpl = (f16*)allocB(PL * 2);
  f16* hoh = (f16*)allocB(PL * 2);  f16* hol = (f16*)allocB(PL * 2);
  f16* o0h = (f16*)allocB(PL * 2);  f16* o0l = (f16*)allocB(PL * 2);
  f16* o1h = (f16*)allocB(PL * 2);  f16* o1l = (f16*)allocB(PL * 2);
  f16* z0h = (f16*)allocB(PL * 2);  f16* z0l = (f16*)allocB(PL * 2);
  float* bbuf   = (float*)allocB(PL * 4);
  float* bfused = (float*)allocB((size_t)kG3N * 4);
  // weight planes
  f16* WfTh = (f16*)allocB(W1 * 3 * 2);  f16* WfTl = (f16*)allocB(W1 * 3 * 2);   // [3072][1024]
  f16* WgBh = (f16*)allocB(W1 * 3 * 2);  f16* WgBl = (f16*)allocB(W1 * 3 * 2);   // [3072][1024]
  f16* Wi2h = (f16*)allocB(W1 * 2);      f16* Wi2l = (f16*)allocB(W1 * 2);       // row-major
  f16* Wi1Th = (f16*)allocB(W1 * 2);     f16* Wi1Tl = (f16*)allocB(W1 * 2);
  f16* Wo1Th = (f16*)allocB(W1 * 2 * 2); f16* Wo1Tl = (f16*)allocB(W1 * 2 * 2);  // [1024][2048]
  f16* Wp1Th = (f16*)allocB(W1 * 2);     f16* Wp1Tl = (f16*)allocB(W1 * 2);
  f16* Wp2Th = (f16*)allocB(W1 * 2);     f16* Wp2Tl = (f16*)allocB(W1 * 2);
  f16* Wo2Th = (f16*)allocB(W1 * 2);     f16* Wo2Tl = (f16*)allocB(W1 * 2);

  // ================= prologue =================
  k_convT<<<dim3(16, 48), 256, 0, stream>>>(Wg, 0, kG3N, 1024, WgTh, WgTl);
  k_convT<<<dim3(16, 48), 256, 0, stream>>>(Wg, 1024, kG3N, 1024, WgBh, WgBl);
  k_convT<<<dim3(16, 16), 256, 0, stream>>>(Wi1, 0, kN1, 1024, Wi1Th, Wi1Tl);
  k_convT<<<dim3(32, 16), 256, 0, stream>>>(Wo1, 0, kN1, 2048, Wo1Th, Wo1Tl);
  k_convT<<<dim3(16, 16), 256, 0, stream>>>(Wp1, 0, kN1, 1024, Wp1Th, Wp1Tl);
  k_convT<<<dim3(16, 16), 256, 0, stream>>>(Wp2, 0, kN1, 1024, Wp2Th, Wp2Tl);
  k_convT<<<dim3(16, 16), 256, 0, stream>>>(Wo2, 0, kN1, 1024, Wo2Th, Wo2Tl);
  k_conv<<<dim3(4096), 256, 0, stream>>>(Wi2, Wi2h, Wi2l);
  k_bfused<<<dim3(12), 256, 0, stream>>>(Wg, bi2, bfused);
  {  // Wfused = Wi2 @ WgTop (fp32 into overlay of Pg)
    MJobs J{};
    J.j[0] = { Wi2h, Wi2l, nullptr, nullptr, WgTh, WgTl, Wfused_tmp, 1024, 1024, kG3N, 0, 1024, 48 };
    k_mgemm<<<dim3(8, 48, 1), 256, 0, stream>>>(J);
  }
  k_convT<<<dim3(16, 48), 256, 0, stream>>>(Wfused_tmp, 0, kG3N, 1024, WfTh, WfTl);
  // WgT region dead from here -> PD/PE reuse it
  k_setup<<<dim3(1024), 256, 0, stream>>>(b0, bbuf, bh, bl);
  k_conv<<<dim3(1024), 256, 0, stream>>>(z0, z0h, z0l);
  k_conv<<<dim3(1024), 256, 0, stream>>>(obs, o0h, o0l);    // obs[0]
  {  // h1(t=0): z0 @ Wi1Top -> PD, then finisher
    MJobs J{};
    J.j[0] = { z0h, z0l, nullptr, nullptr, Wi1Th, Wi1Tl, PD, 1024, 1024, kN1, 0, 1024, 16 };
    k_mgemm<<<dim3(2, 16, 1), 256, 0, stream>>>(J);
  }
  k_finish0<<<dim3(4, kB), 256, 0, stream>>>(PD, Wi1, bi1, acts, h1h, h1l);

  // ================= the scan =================
  for (int t = 0; t < kT; ++t) {
    const float* unz_t = unz + (size_t)t * kB * kN1;
    f16* oth = (t & 1) ? o1h : o0h;
    f16* otl = (t & 1) ? o1l : o0l;
    f16* onh = (t & 1) ? o0h : o1h;
    f16* onl = (t & 1) ? o0l : o1l;

    {  // gates: Pg[0..1] = h1 @ WfT (splitK2) ; Pg[2..3] = b @ WgB (splitK2)
      MJobs J{};
      J.j[0] = { h1h, h1l, nullptr, nullptr, WfTh, WfTl, Pg,          1024, 1024, kG3N, 0,   512, 48 };
      J.j[1] = { h1h, h1l, nullptr, nullptr, WfTh, WfTl, Pg + S3,     1024, 1024, kG3N, 512, 512, 48 };
      J.j[2] = { bh,  bl,  nullptr, nullptr, WgBh, WgBl, Pg + 2 * S3, 1024, 1024, kG3N, 0,   512, 48 };
      J.j[3] = { bh,  bl,  nullptr, nullptr, WgBh, WgBl, Pg + 3 * S3, 1024, 1024, kG3N, 512, 512, 48 };
      k_mgemm<<<dim3(2, 48, 4), 256, 0, stream>>>(J);
    }
    k_gru<<<dim3(kB), 256, 0, stream>>>(Pg, bfused, lns, lnb, bbuf, bh, bl,
                                        obs + (size_t)(t + 1) * kB * kN1, onh, onl,
                                        (t < kT - 1) ? 1 : 0);
    {  // D: PD[0..1] = b @ Wp1T (splitK2) ; PD[2..5] = [obs,b] @ Wo1T (splitK4)
      MJobs J{};
      J.j[0] = { bh,  bl,  nullptr, nullptr, Wp1Th, Wp1Tl, PD,          1024, 1024, kN1, 0,    512, 16 };
      J.j[1] = { bh,  bl,  nullptr, nullptr, Wp1Th, Wp1Tl, PD + PL,     1024, 1024, kN1, 512,  512, 16 };
      J.j[2] = { oth, otl, bh, bl,           Wo1Th, Wo1Tl, PD + 2 * PL, 1024, 2048, kN1, 0,    512, 16 };
      J.j[3] = { oth, otl, bh, bl,           Wo1Th, Wo1Tl, PD + 3 * PL, 1024, 2048, kN1, 512,  512, 16 };
      J.j[4] = { oth, otl, bh, bl,           Wo1Th, Wo1Tl, PD + 4 * PL, 1024, 2048, kN1, 1024, 512, 16 };
      J.j[5] = { oth, otl, bh, bl,           Wo1Th, Wo1Tl, PD + 5 * PL, 1024, 2048, kN1, 1536, 512, 16 };
      k_mgemm<<<dim3(2, 16, 6), 256, 0, stream>>>(J);
    }
    {  // combine: hp = silu(sum2 + bp1) ; ho = silu(sum4 + bo1)
      CJobs C{};
      C.j[0] = { PD,          2, bp1, hph, hpl };
      C.j[1] = { PD + 2 * PL, 4, bo1, hoh, hol };
      k_comb<<<dim3(1024, 2), 256, 0, stream>>>(C);
    }
    {  // E: PE[0..1] = hp @ Wp2T ; PE[2..3] = ho @ Wo2T (splitK2 each)
      MJobs J{};
      J.j[0] = { hph, hpl, nullptr, nullptr, Wp2Th, Wp2Tl, PE,          1024, 1024, kN1, 0,   512, 16 };
      J.j[1] = { hph, hpl, nullptr, nullptr, Wp2Th, Wp2Tl, PE + PL,     1024, 1024, kN1, 512, 512, 16 };
      J.j[2] = { hoh, hol, nullptr, nullptr, Wo2Th, Wo2Tl, PE + 2 * PL, 1024, 1024, kN1, 0,   512, 16 };
      J.j[3] = { hoh, hol, nullptr, nullptr, Wo2Th, Wo2Tl, PE + 3 * PL, 1024, 1024, kN1, 512, 512, 16 };
      k_mgemm<<<dim3(2, 16, 4), 256, 0, stream>>>(J);
    }
    k_sample<<<dim3(kB), 1024, 0, stream>>>(PE, bp2, bo2, unz_t,
                                            out + (size_t)t * kB,
                                            Wi1, bi1, acts + (size_t)(t + 1) * kB * kActD,
                                            h1h, h1l, (t < kT - 1) ? 1 : 0);
  }
}